// Round 14
// baseline (891.988 us; speedup 1.0000x reference)
//
#include <hip/hip_runtime.h>

#define NADDR 400000
#define NTX   400000
#define NEDGE 1500000
#define FIN   64
#define HID   32
#define NB    1563        // buckets per node type; 256 nodes per bucket
#define LSTR  36          // LDS row stride (floats) in k_preS2
#define HSTR  36          // LDS row stride (floats) in k_aggE
#define NND   400000

static inline int cdiv_host(long a, int b) { return (int)((a + b - 1) / b); }

__device__ __forceinline__ unsigned short f2bf(float f) {
    unsigned b = __float_as_uint(f);
    b += 0x7FFFu + ((b >> 16) & 1u);          // round-to-nearest-even
    return (unsigned short)(b >> 16);
}
__device__ __forceinline__ float bf2f(unsigned short s) {
    return __uint_as_float(((unsigned)s) << 16);
}
__device__ __forceinline__ unsigned pack2bf(float a, float b) {
    return (unsigned)f2bf(a) | ((unsigned)f2bf(b) << 16);
}

// ================= bucketed CSR build (verified round-4 chain) ==============

__global__ void k_hist(const int* __restrict__ at_dst, const int* __restrict__ ta_dst,
                       int* __restrict__ bcnt /*[2*NB]*/, int GH) {
    __shared__ int h[NB];
    bool wh = blockIdx.x >= GH;
    int blk = blockIdx.x - (wh ? GH : 0);
    const int* dst = wh ? ta_dst : at_dst;
    for (int i = threadIdx.x; i < NB; i += 256) h[i] = 0;
    __syncthreads();
    for (long e = (long)blk * 256 + threadIdx.x; e < NEDGE; e += (long)GH * 256)
        atomicAdd(&h[dst[e] >> 8], 1);
    __syncthreads();
    int* g = bcnt + (wh ? NB : 0);
    for (int i = threadIdx.x; i < NB; i += 256) {
        int v = h[i];
        if (v) atomicAdd(&g[i], v);
    }
}

__global__ void k_scan_nb(const int* __restrict__ bcnt, int* __restrict__ bbase,
                          int* __restrict__ gcur) {
    __shared__ int sm[256];
    __shared__ int carry;
    int w = blockIdx.x;
    int t = threadIdx.x;
    if (t == 0) carry = 0;
    __syncthreads();
    for (int base = 0; base < NB; base += 256) {
        int i = base + t;
        int v = (i < NB) ? bcnt[w * NB + i] : 0;
        sm[t] = v;
        __syncthreads();
        for (int off = 1; off < 256; off <<= 1) {
            int x = (t >= off) ? sm[t - off] : 0;
            __syncthreads();
            sm[t] += x;
            __syncthreads();
        }
        int excl = sm[t] - v + carry;
        if (i < NB) { bbase[w * (NB + 1) + i] = excl; gcur[w * NB + i] = excl; }
        int tot = sm[255];
        __syncthreads();
        if (t == 0) carry += tot;
        __syncthreads();
    }
    if (t == 0) bbase[w * (NB + 1) + NB] = NEDGE;
}

__global__ void k_dist(const int* __restrict__ ei_at, const int* __restrict__ ei_ta,
                       int* __restrict__ gcur, unsigned* __restrict__ eb_at,
                       unsigned* __restrict__ eb_ta, int GD) {
    __shared__ int h[NB];
    __shared__ int bs[NB];
    bool wh = blockIdx.x >= GD;
    int blk = blockIdx.x - (wh ? GD : 0);
    const int* ei = wh ? ei_ta : ei_at;
    unsigned* eb = wh ? eb_ta : eb_at;
    for (int i = threadIdx.x; i < NB; i += 256) h[i] = 0;
    __syncthreads();
    long e0 = (long)blk * 256 + threadIdx.x;
    long stride = (long)GD * 256;
    for (long e = e0; e < NEDGE; e += stride)
        atomicAdd(&h[ei[NEDGE + e] >> 8], 1);
    __syncthreads();
    int* gc = gcur + (wh ? NB : 0);
    for (int i = threadIdx.x; i < NB; i += 256) {
        int c = h[i];
        bs[i] = c ? atomicAdd(&gc[i], c) : 0;
        h[i] = 0;
    }
    __syncthreads();
    for (long e = e0; e < NEDGE; e += stride) {
        int d = ei[NEDGE + e];
        int s = ei[e];
        int b = d >> 8;
        int r = atomicAdd(&h[b], 1);
        eb[bs[b] + r] = ((unsigned)s << 8) | (unsigned)(d & 255);
    }
}

__global__ void k_csrb(const unsigned* __restrict__ eb_at, const unsigned* __restrict__ eb_ta,
                       const int* __restrict__ bbase,
                       int* __restrict__ rp_tx, int* __restrict__ rp_ad,
                       int* __restrict__ col_at, int* __restrict__ col_ta) {
    __shared__ int deg[256];
    __shared__ int cur[256];
    __shared__ int sm[256];
    bool wh = blockIdx.x >= NB;
    int b = blockIdx.x - (wh ? NB : 0);
    const unsigned* eb = wh ? eb_ta : eb_at;
    int* rp  = wh ? rp_ad  : rp_tx;
    int* col = wh ? col_ta : col_at;
    const int* bb = bbase + (wh ? (NB + 1) : 0);
    int e0 = bb[b], e1 = bb[b + 1];
    int t = threadIdx.x;
    deg[t] = 0;
    __syncthreads();
    for (int e = e0 + t; e < e1; e += 256)
        atomicAdd(&deg[eb[e] & 255], 1);
    __syncthreads();
    int v = deg[t];
    sm[t] = v;
    __syncthreads();
    for (int off = 1; off < 256; off <<= 1) {
        int x = (t >= off) ? sm[t - off] : 0;
        __syncthreads();
        sm[t] += x;
        __syncthreads();
    }
    int excl = sm[t] - v;
    int node = b * 256 + t;
    if (node < NND) rp[node] = e0 + excl;
    cur[t] = e0 + excl;
    __syncthreads();
    for (int e = e0 + t; e < e1; e += 256) {
        unsigned p = eb[e];
        int idx = atomicAdd(&cur[p & 255], 1);
        col[idx] = (int)(p >> 8);
    }
    if (t == 0 && b == 0) rp[NND] = NEDGE;
}

// ================= L1 dual pre-transform (round-10/11 proven + bf16 outa) ===
// 128 threads / 128 rows per block. Input staged via LDS (coalesced). All
// stores staged through LDS for group-coalesced full-line writes: outa as
// packed-bf16 uints (padded stride-17), outb as fp32 (stride LSTR).
// Grid is exact: 400000 / 128 = 3125, no row guards needed.
__global__ __launch_bounds__(128)
void k_preS2(const float* __restrict__ x,
             const float* __restrict__ wa, unsigned short* __restrict__ outa,
             const float* __restrict__ wb, const float* __restrict__ bb,
             float* __restrict__ outb, int n) {
    __shared__ alignas(16) float xs[128 * LSTR];   // 18432 B
    int t = threadIdx.x;
    long row0 = (long)blockIdx.x * 128;

    float aa[HID], ab[HID];
#pragma unroll
    for (int j = 0; j < HID; ++j) { aa[j] = 0.0f; ab[j] = bb[j]; }

    for (int kt = 0; kt < FIN / 32; ++kt) {
        if (kt) __syncthreads();
#pragma unroll
        for (int sub = 0; sub < 8; ++sub) {
            int f = sub * 128 + t;
            int r = f >> 3, k4 = f & 7;
            *(float4*)(&xs[r * LSTR + k4 * 4]) =
                *(const float4*)(x + (row0 + r) * FIN + kt * 32 + k4 * 4);
        }
        __syncthreads();
        float xr[32];
#pragma unroll
        for (int q = 0; q < 8; ++q) {
            float4 v = *(const float4*)(&xs[t * LSTR + q * 4]);
            xr[q * 4] = v.x; xr[q * 4 + 1] = v.y; xr[q * 4 + 2] = v.z; xr[q * 4 + 3] = v.w;
        }
        const float* wka = wa + kt * 32 * HID;
        const float* wkb = wb + kt * 32 * HID;
#pragma unroll
        for (int k = 0; k < 32; ++k) {
            float xk = xr[k];
            const float* ra = wka + k * HID;
            const float* rb = wkb + k * HID;
#pragma unroll
            for (int j = 0; j < HID; ++j) {
                aa[j] = __builtin_fmaf(xk, ra[j], aa[j]);
                ab[j] = __builtin_fmaf(xk, rb[j], ab[j]);
            }
        }
    }

    // ---- store outa (bf16) via LDS repack: row = 16 uints, pad stride 17 ----
    __syncthreads();
    unsigned* lu = (unsigned*)xs;
#pragma unroll
    for (int q = 0; q < 16; ++q)
        lu[t * 17 + q] = pack2bf(aa[2 * q], aa[2 * q + 1]);
    __syncthreads();
    unsigned* oa32 = (unsigned*)outa + row0 * 16;
#pragma unroll
    for (int k = 0; k < 16; ++k) {
        int gi = k * 128 + t;
        oa32[gi] = lu[(gi >> 4) * 17 + (gi & 15)];
    }
    // ---- store outb (fp32) via LDS, full-line coalesced ----
    __syncthreads();
#pragma unroll
    for (int j = 0; j < HID; j += 4)
        *(float4*)(&xs[t * LSTR + j]) = make_float4(ab[j], ab[j + 1], ab[j + 2], ab[j + 3]);
    __syncthreads();
#pragma unroll
    for (int sub = 0; sub < 8; ++sub) {
        int f = sub * 128 + t;
        int r = f >> 3, k4 = f & 7;
        *(float4*)(outb + (row0 + r) * HID + k4 * 4) = *(const float4*)(&xs[r * LSTR + k4 * 4]);
    }
}

// ================= fused SAGE aggregation + dense epilogue ==================
// Phase 1 restructured for MLP: node-PAIRS processed with hoisted rp loads and
// straight-line masked first-8 gathers (16 col + 16 row loads in flight per
// thread); dynamic tail loop only for deg>8 (P~1.3%/node).
template<int EP, bool A16>
__global__ __launch_bounds__(256)
void k_aggE(const int* __restrict__ rp, const int* __restrict__ col,
            const unsigned short* __restrict__ preL, const float* preR,
            const float* __restrict__ wA, const float* __restrict__ bA, void* outA,
            const float* __restrict__ wB, const float* __restrict__ bB, float* outB,
            int n) {
    __shared__ alignas(16) float hh[256 * HSTR];   // 36864 B
    int t = threadIdx.x;
    long row0 = (long)blockIdx.x * 256;
    int u = t & 7;
    int lnb = t >> 3;   // 0..31

    // ---- phase 1: gather + finalize h into LDS (4 passes x 2 nodes) ----
#pragma unroll
    for (int bp = 0; bp < 4; ++bp) {
        int lnA = (2 * bp) * 32 + lnb;
        int lnB = (2 * bp + 1) * 32 + lnb;
        long gA = row0 + lnA;
        long gB = row0 + lnB;
        bool okA = gA < n, okB = gB < n;
        long cA = okA ? gA : (n - 1);
        long cB = okB ? gB : (n - 1);
        int a0 = rp[cA], a1 = rp[cA + 1];
        int b0 = rp[cB], b1 = rp[cB + 1];
        int cntA = a1 - a0, cntB = b1 - b0;

        int ia[8], ib[8];
#pragma unroll
        for (int q = 0; q < 8; ++q) {
            int ea = a0 + (q < cntA ? q : (cntA > 0 ? cntA - 1 : 0));
            int eb = b0 + (q < cntB ? q : (cntB > 0 ? cntB - 1 : 0));
            ia[q] = col[ea < NEDGE ? ea : NEDGE - 1];
            ib[q] = col[eb < NEDGE ? eb : NEDGE - 1];
        }
        ushort4 va[8], vb[8];
#pragma unroll
        for (int q = 0; q < 8; ++q) {
            va[q] = *(const ushort4*)(preL + (size_t)ia[q] * HID + u * 4);
            vb[q] = *(const ushort4*)(preL + (size_t)ib[q] * HID + u * 4);
        }
        float axA = 0, ayA = 0, azA = 0, awA = 0;
        float axB = 0, ayB = 0, azB = 0, awB = 0;
#pragma unroll
        for (int q = 0; q < 8; ++q) {
            if (q < cntA) {
                axA += bf2f(va[q].x); ayA += bf2f(va[q].y);
                azA += bf2f(va[q].z); awA += bf2f(va[q].w);
            }
            if (q < cntB) {
                axB += bf2f(vb[q].x); ayB += bf2f(vb[q].y);
                azB += bf2f(vb[q].z); awB += bf2f(vb[q].w);
            }
        }
        // rare tails (deg > 8)
        for (int k = a0 + 8; k < a1; ++k) {
            int s = col[k];
            ushort4 v = *(const ushort4*)(preL + (size_t)s * HID + u * 4);
            axA += bf2f(v.x); ayA += bf2f(v.y); azA += bf2f(v.z); awA += bf2f(v.w);
        }
        for (int k = b0 + 8; k < b1; ++k) {
            int s = col[k];
            ushort4 v = *(const ushort4*)(preL + (size_t)s * HID + u * 4);
            axB += bf2f(v.x); ayB += bf2f(v.y); azB += bf2f(v.z); awB += bf2f(v.w);
        }

        if (okA) {
            float inv = 1.0f / fmaxf((float)cntA, 1.0f);
            float4 r = *(const float4*)(preR + (size_t)gA * HID + u * 4);
            float* hp = &hh[lnA * HSTR + u * 4];
            hp[0] = fmaxf(__builtin_fmaf(axA, inv, r.x), 0.0f);
            hp[1] = fmaxf(__builtin_fmaf(ayA, inv, r.y), 0.0f);
            hp[2] = fmaxf(__builtin_fmaf(azA, inv, r.z), 0.0f);
            hp[3] = fmaxf(__builtin_fmaf(awA, inv, r.w), 0.0f);
        }
        if (okB) {
            float inv = 1.0f / fmaxf((float)cntB, 1.0f);
            float4 r = *(const float4*)(preR + (size_t)gB * HID + u * 4);
            float* hp = &hh[lnB * HSTR + u * 4];
            hp[0] = fmaxf(__builtin_fmaf(axB, inv, r.x), 0.0f);
            hp[1] = fmaxf(__builtin_fmaf(ayB, inv, r.y), 0.0f);
            hp[2] = fmaxf(__builtin_fmaf(azB, inv, r.z), 0.0f);
            hp[3] = fmaxf(__builtin_fmaf(awB, inv, r.w), 0.0f);
        }
    }
    __syncthreads();

    // ---- phase 2: dense epilogue (unchanged, proven) ----
    long gd = row0 + t;
    if (gd >= n) return;
    float rrow[32];
#pragma unroll
    for (int q = 0; q < 8; ++q) {
        float4 v = *(const float4*)(&hh[t * HSTR + q * 4]);
        rrow[q * 4] = v.x; rrow[q * 4 + 1] = v.y;
        rrow[q * 4 + 2] = v.z; rrow[q * 4 + 3] = v.w;
    }

    if (EP == 2) {
        float o0 = bA[0], o1 = bA[1];
#pragma unroll
        for (int k = 0; k < HID; ++k) {
            o0 = __builtin_fmaf(rrow[k], wA[k * 2 + 0], o0);
            o1 = __builtin_fmaf(rrow[k], wA[k * 2 + 1], o1);
        }
        float* oo = (float*)outA;
        oo[gd * 2 + 0] = o0;
        oo[gd * 2 + 1] = o1;
        return;
    }

    {
        float acc[HID];
#pragma unroll
        for (int j = 0; j < HID; ++j) acc[j] = bA ? bA[j] : 0.0f;
#pragma unroll
        for (int k = 0; k < HID; ++k) {
            float rk = rrow[k];
            const float* wr = wA + k * HID;
#pragma unroll
            for (int j = 0; j < HID; ++j) acc[j] = __builtin_fmaf(rk, wr[j], acc[j]);
        }
        if (A16) {
            uint4* o = (uint4*)((unsigned short*)outA + gd * HID);
#pragma unroll
            for (int q = 0; q < 4; ++q) {
                unsigned w0 = pack2bf(acc[q * 8 + 0], acc[q * 8 + 1]);
                unsigned w1 = pack2bf(acc[q * 8 + 2], acc[q * 8 + 3]);
                unsigned w2 = pack2bf(acc[q * 8 + 4], acc[q * 8 + 5]);
                unsigned w3 = pack2bf(acc[q * 8 + 6], acc[q * 8 + 7]);
                o[q] = make_uint4(w0, w1, w2, w3);
            }
        } else {
            float* o = (float*)outA + (size_t)gd * HID;
#pragma unroll
            for (int j = 0; j < HID; j += 4)
                *(float4*)(o + j) = make_float4(acc[j], acc[j + 1], acc[j + 2], acc[j + 3]);
        }
    }
    if (EP == 0) {
        float acc[HID];
#pragma unroll
        for (int j = 0; j < HID; ++j) acc[j] = bB[j];
#pragma unroll
        for (int k = 0; k < HID; ++k) {
            float rk = rrow[k];
            const float* wr = wB + k * HID;
#pragma unroll
            for (int j = 0; j < HID; ++j) acc[j] = __builtin_fmaf(rk, wr[j], acc[j]);
        }
        float* o = outB + (size_t)gd * HID;
#pragma unroll
        for (int j = 0; j < HID; j += 4)
            *(float4*)(o + j) = make_float4(acc[j], acc[j + 1], acc[j + 2], acc[j + 3]);
    }
}

// ============================================================================

extern "C" void kernel_launch(void* const* d_in, const int* in_sizes, int n_in,
                              void* d_out, int out_size, void* d_ws, size_t ws_size,
                              hipStream_t stream) {
    const float* x_addr  = (const float*)d_in[0];
    const float* x_tx    = (const float*)d_in[1];
    const int*   ei_at   = (const int*)d_in[2];
    const int*   ei_ta   = (const int*)d_in[3];
    const float* w1_tx_l = (const float*)d_in[4];  const float* b1_tx = (const float*)d_in[5];
    const float* w1_tx_r = (const float*)d_in[6];
    const float* w1_ad_l = (const float*)d_in[7];  const float* b1_ad = (const float*)d_in[8];
    const float* w1_ad_r = (const float*)d_in[9];
    const float* w2_tx_l = (const float*)d_in[10]; const float* b2_tx = (const float*)d_in[11];
    const float* w2_tx_r = (const float*)d_in[12];
    const float* w2_ad_l = (const float*)d_in[13]; const float* b2_ad = (const float*)d_in[14];
    const float* w2_ad_r = (const float*)d_in[15];
    // d_in[16..18] unused (w3_tx_*)
    const float* w3_ad_l = (const float*)d_in[19]; const float* b3_ad = (const float*)d_in[20];
    const float* w3_ad_r = (const float*)d_in[21];
    const float* w_out   = (const float*)d_in[22]; const float* b_out = (const float*)d_in[23];
    float* out = (float*)d_out;

    // ---- workspace carve (5 fp32-sized slots; bf16 buffers reuse slots) ----
    char* base = (char*)d_ws;
    int* bcnt   = (int*)base;  base += (size_t)(2 * NB) * 4;
    int* bbase  = (int*)base;  base += (size_t)(2 * (NB + 1)) * 4;
    int* gcur   = (int*)base;  base += (size_t)(2 * NB) * 4;
    int* rp_tx  = (int*)base;  base += (size_t)(NND + 1) * 4;
    int* rp_ad  = (int*)base;  base += (size_t)(NND + 1) * 4;
    int* col_at = (int*)base;  base += (size_t)NEDGE * 4;
    int* col_ta = (int*)base;  base += (size_t)NEDGE * 4;
    base = (char*)(((size_t)base + 255) & ~(size_t)255);
    const size_t SLOT = (size_t)NND * HID;   // floats per slot
    char* S0 = base;                          // slot 0 overlays eb region (dead after build)
    unsigned* eb_at = (unsigned*)base;        // build-only
    unsigned* eb_ta = eb_at + (size_t)NEDGE;
    char* S1 = S0 + SLOT * 4;
    char* S2 = S1 + SLOT * 4;
    char* S3 = S2 + SLOT * 4;
    char* S4 = S3 + SLOT * 4;

    // roles: bf16 preL buffers and fp32 preR buffers
    unsigned short* pLtx  = (unsigned short*)S1;  // L1 pL-tx   (from x_addr)
    unsigned short* pLad  = (unsigned short*)S2;  // L1 pL-ad   (from x_tx)
    float*          pRad  = (float*)S3;           // L1 pR-ad
    float*          pRtx  = (float*)S4;           // L1 pR-tx -> in-place pR-tx2
    unsigned short* pLad2 = (unsigned short*)S0;  // TX@w2_ad_l
    unsigned short* pLtx2 = (unsigned short*)S1;  // AD@w2_tx_l (overwrites pLtx, dead)
    float*          pRad2 = (float*)S3;           // AD@w2_ad_r (in-place on pRad)
    unsigned short* pLad3 = (unsigned short*)S2;  // TX2@w3_ad_l (overwrites pLad, dead)
    float*          pRad3 = (float*)S3;           // AD2@w3_ad_r (in-place on pRad2)

    dim3 blk(256);
    dim3 blk128(128);
    int gS = cdiv_host(NND, 128);                 // 3125 (exact: 3125*128 = 400000)
    int gB = cdiv_host(NND, 256);                 // 1563 (k_aggE)
    const int GH = 96, GD = 192;

    // ---- bucketed CSR build ----
    hipMemsetAsync(bcnt, 0, (size_t)(2 * NB) * 4, stream);
    k_hist<<<2 * GH, blk, 0, stream>>>(ei_at + NEDGE, ei_ta + NEDGE, bcnt, GH);
    k_scan_nb<<<2, blk, 0, stream>>>(bcnt, bbase, gcur);
    k_dist<<<2 * GD, blk, 0, stream>>>(ei_at, ei_ta, gcur, eb_at, eb_ta, GD);
    k_csrb<<<2 * NB, blk, 0, stream>>>(eb_at, eb_ta, bbase, rp_tx, rp_ad, col_at, col_ta);

    // ---- layer 1 pre-transforms (dual, LDS-staged loads AND stores) ----
    k_preS2<<<gS, blk128, 0, stream>>>(x_addr, w1_tx_l, pLtx, w1_ad_r, b1_ad, pRad, NADDR);
    k_preS2<<<gS, blk128, 0, stream>>>(x_tx,  w1_ad_l, pLad, w1_tx_r, b1_tx, pRtx, NTX);

    // ---- L1 aggs with fused L2 pre-transforms ----
    k_aggE<0, true><<<gB, blk, 0, stream>>>(rp_tx, col_at, pLtx, pRtx,
                                            w2_ad_l, nullptr, pLad2,
                                            w2_tx_r, b2_tx, pRtx, NTX);
    k_aggE<0, true><<<gB, blk, 0, stream>>>(rp_ad, col_ta, pLad, pRad,
                                            w2_tx_l, nullptr, pLtx2,
                                            w2_ad_r, b2_ad, pRad2, NADDR);

    // ---- L2 aggs with fused L3 pre-transforms ----
    k_aggE<1, true><<<gB, blk, 0, stream>>>(rp_tx, col_at, pLtx2, pRtx,
                                            w3_ad_l, nullptr, pLad3,
                                            nullptr, nullptr, nullptr, NTX);
    k_aggE<1, false><<<gB, blk, 0, stream>>>(rp_ad, col_ta, pLad2, pRad2,
                                             w3_ad_r, b3_ad, pRad3,
                                             nullptr, nullptr, nullptr, NADDR);

    // ---- L3 agg + classifier ----
    k_aggE<2, false><<<gB, blk, 0, stream>>>(rp_ad, col_ta, pLad3, pRad3,
                                             w_out, b_out, out,
                                             nullptr, nullptr, nullptr, NADDR);
}

// Round 20
// 675.110 us; speedup vs baseline: 1.3212x; 1.3212x over previous
//
#include <hip/hip_runtime.h>

#define NADDR 400000
#define NTX   400000
#define NEDGE 1500000
#define FIN   64
#define HID   32
#define NB    1563        // buckets per node type; 256 nodes per bucket
#define LSTR  36          // LDS row stride (floats) in k_preS2
#define HSTR  36          // LDS row stride (floats) in k_aggE (144B, 16B-aligned)
#define NND   400000

static inline int cdiv_host(long a, int b) { return (int)((a + b - 1) / b); }

// ================= bucketed CSR build (verified round-4 chain) ==============

__global__ void k_hist(const int* __restrict__ at_dst, const int* __restrict__ ta_dst,
                       int* __restrict__ bcnt /*[2*NB]*/, int GH) {
    __shared__ int h[NB];
    bool wh = blockIdx.x >= GH;
    int blk = blockIdx.x - (wh ? GH : 0);
    const int* dst = wh ? ta_dst : at_dst;
    for (int i = threadIdx.x; i < NB; i += 256) h[i] = 0;
    __syncthreads();
    for (long e = (long)blk * 256 + threadIdx.x; e < NEDGE; e += (long)GH * 256)
        atomicAdd(&h[dst[e] >> 8], 1);
    __syncthreads();
    int* g = bcnt + (wh ? NB : 0);
    for (int i = threadIdx.x; i < NB; i += 256) {
        int v = h[i];
        if (v) atomicAdd(&g[i], v);
    }
}

__global__ void k_scan_nb(const int* __restrict__ bcnt, int* __restrict__ bbase,
                          int* __restrict__ gcur) {
    __shared__ int sm[256];
    __shared__ int carry;
    int w = blockIdx.x;
    int t = threadIdx.x;
    if (t == 0) carry = 0;
    __syncthreads();
    for (int base = 0; base < NB; base += 256) {
        int i = base + t;
        int v = (i < NB) ? bcnt[w * NB + i] : 0;
        sm[t] = v;
        __syncthreads();
        for (int off = 1; off < 256; off <<= 1) {
            int x = (t >= off) ? sm[t - off] : 0;
            __syncthreads();
            sm[t] += x;
            __syncthreads();
        }
        int excl = sm[t] - v + carry;
        if (i < NB) { bbase[w * (NB + 1) + i] = excl; gcur[w * NB + i] = excl; }
        int tot = sm[255];
        __syncthreads();
        if (t == 0) carry += tot;
        __syncthreads();
    }
    if (t == 0) bbase[w * (NB + 1) + NB] = NEDGE;
}

__global__ void k_dist(const int* __restrict__ ei_at, const int* __restrict__ ei_ta,
                       int* __restrict__ gcur, unsigned* __restrict__ eb_at,
                       unsigned* __restrict__ eb_ta, int GD) {
    __shared__ int h[NB];
    __shared__ int bs[NB];
    bool wh = blockIdx.x >= GD;
    int blk = blockIdx.x - (wh ? GD : 0);
    const int* ei = wh ? ei_ta : ei_at;
    unsigned* eb = wh ? eb_ta : eb_at;
    for (int i = threadIdx.x; i < NB; i += 256) h[i] = 0;
    __syncthreads();
    long e0 = (long)blk * 256 + threadIdx.x;
    long stride = (long)GD * 256;
    for (long e = e0; e < NEDGE; e += stride)
        atomicAdd(&h[ei[NEDGE + e] >> 8], 1);
    __syncthreads();
    int* gc = gcur + (wh ? NB : 0);
    for (int i = threadIdx.x; i < NB; i += 256) {
        int c = h[i];
        bs[i] = c ? atomicAdd(&gc[i], c) : 0;
        h[i] = 0;
    }
    __syncthreads();
    for (long e = e0; e < NEDGE; e += stride) {
        int d = ei[NEDGE + e];
        int s = ei[e];
        int b = d >> 8;
        int r = atomicAdd(&h[b], 1);
        eb[bs[b] + r] = ((unsigned)s << 8) | (unsigned)(d & 255);
    }
}

__global__ void k_csrb(const unsigned* __restrict__ eb_at, const unsigned* __restrict__ eb_ta,
                       const int* __restrict__ bbase,
                       int* __restrict__ rp_tx, int* __restrict__ rp_ad,
                       int* __restrict__ col_at, int* __restrict__ col_ta) {
    __shared__ int deg[256];
    __shared__ int cur[256];
    __shared__ int sm[256];
    bool wh = blockIdx.x >= NB;
    int b = blockIdx.x - (wh ? NB : 0);
    const unsigned* eb = wh ? eb_ta : eb_at;
    int* rp  = wh ? rp_ad  : rp_tx;
    int* col = wh ? col_ta : col_at;
    const int* bb = bbase + (wh ? (NB + 1) : 0);
    int e0 = bb[b], e1 = bb[b + 1];
    int t = threadIdx.x;
    deg[t] = 0;
    __syncthreads();
    for (int e = e0 + t; e < e1; e += 256)
        atomicAdd(&deg[eb[e] & 255], 1);
    __syncthreads();
    int v = deg[t];
    sm[t] = v;
    __syncthreads();
    for (int off = 1; off < 256; off <<= 1) {
        int x = (t >= off) ? sm[t - off] : 0;
        __syncthreads();
        sm[t] += x;
        __syncthreads();
    }
    int excl = sm[t] - v;
    int node = b * 256 + t;
    if (node < NND) rp[node] = e0 + excl;
    cur[t] = e0 + excl;
    __syncthreads();
    for (int e = e0 + t; e < e1; e += 256) {
        unsigned p = eb[e];
        int idx = atomicAdd(&cur[p & 255], 1);
        col[idx] = (int)(p >> 8);
    }
    if (t == 0 && b == 0) rp[NND] = NEDGE;
}

// ================= L1 dual pre-transform (round-10 proven) ==================
__global__ __launch_bounds__(128)
void k_preS2(const float* __restrict__ x,
             const float* __restrict__ wa, float* __restrict__ outa,
             const float* __restrict__ wb, const float* __restrict__ bb,
             float* __restrict__ outb, int n) {
    __shared__ alignas(16) float xs[128 * LSTR];   // 18432 B
    int t = threadIdx.x;
    long row0 = (long)blockIdx.x * 128;

    float aa[HID], ab[HID];
#pragma unroll
    for (int j = 0; j < HID; ++j) { aa[j] = 0.0f; ab[j] = bb[j]; }

    for (int kt = 0; kt < FIN / 32; ++kt) {
        if (kt) __syncthreads();
#pragma unroll
        for (int sub = 0; sub < 8; ++sub) {
            int f = sub * 128 + t;
            int r = f >> 3, k4 = f & 7;
            long gr = row0 + r;
            if (gr >= n) gr = n - 1;
            *(float4*)(&xs[r * LSTR + k4 * 4]) =
                *(const float4*)(x + gr * FIN + kt * 32 + k4 * 4);
        }
        __syncthreads();
        float xr[32];
#pragma unroll
        for (int q = 0; q < 8; ++q) {
            float4 v = *(const float4*)(&xs[t * LSTR + q * 4]);
            xr[q * 4] = v.x; xr[q * 4 + 1] = v.y; xr[q * 4 + 2] = v.z; xr[q * 4 + 3] = v.w;
        }
        const float* wka = wa + kt * 32 * HID;
        const float* wkb = wb + kt * 32 * HID;
#pragma unroll
        for (int k = 0; k < 32; ++k) {
            float xk = xr[k];
            const float* ra = wka + k * HID;
            const float* rb = wkb + k * HID;
#pragma unroll
            for (int j = 0; j < HID; ++j) {
                aa[j] = __builtin_fmaf(xk, ra[j], aa[j]);
                ab[j] = __builtin_fmaf(xk, rb[j], ab[j]);
            }
        }
    }

    // store outa then outb via LDS, full-line coalesced
    __syncthreads();
#pragma unroll
    for (int j = 0; j < HID; j += 4)
        *(float4*)(&xs[t * LSTR + j]) = make_float4(aa[j], aa[j + 1], aa[j + 2], aa[j + 3]);
    __syncthreads();
#pragma unroll
    for (int sub = 0; sub < 8; ++sub) {
        int f = sub * 128 + t;
        int r = f >> 3, k4 = f & 7;
        long gr = row0 + r;
        if (gr < n)
            *(float4*)(outa + gr * HID + k4 * 4) = *(const float4*)(&xs[r * LSTR + k4 * 4]);
    }
    __syncthreads();
#pragma unroll
    for (int j = 0; j < HID; j += 4)
        *(float4*)(&xs[t * LSTR + j]) = make_float4(ab[j], ab[j + 1], ab[j + 2], ab[j + 3]);
    __syncthreads();
#pragma unroll
    for (int sub = 0; sub < 8; ++sub) {
        int f = sub * 128 + t;
        int r = f >> 3, k4 = f & 7;
        long gr = row0 + r;
        if (gr < n)
            *(float4*)(outb + gr * HID + k4 * 4) = *(const float4*)(&xs[r * LSTR + k4 * 4]);
    }
}

// ================= fused SAGE aggregation + dense epilogue ==================
// Block = 256 threads = 256 dst nodes. Phase 1: 8 sub-batches of 32 nodes
// (8 lanes/node) run the proven gather (8-deep clamped unroll) + preR add +
// relu, writing h rows into LDS. Phase 2 (after one barrier): thread t owns
// node row0+t, pulls its h row from LDS into registers, and applies the NEXT
// layer's transform(s) with wave-uniform (scalar-cached) weights, storing
// full coalesced 128B rows.
//   EP=0 (dual):   outA = h@wA (+bA), outB = h@wB + bB
//   EP=1 (single): outA = h@wA (+bA)
//   EP=2 (final):  outA[n,2] = h@wA + bA   (wA is [32,2])
// preR may alias outA/outB: each row is read (pre-barrier) only by its own
// block and written (post-barrier) only by its own block.
template<int EP>
__global__ __launch_bounds__(256)
void k_aggE(const int* __restrict__ rp, const int* __restrict__ col,
            const float* __restrict__ preL, const float* preR,
            const float* __restrict__ wA, const float* __restrict__ bA, float* outA,
            const float* __restrict__ wB, const float* __restrict__ bB, float* outB,
            int n) {
    __shared__ alignas(16) float hh[256 * HSTR];   // 36864 B
    int t = threadIdx.x;
    long row0 = (long)blockIdx.x * 256;
    int u = t & 7;
    int lnb = t >> 3;   // 0..31

    // ---- phase 1: gather + finalize h into LDS (8 batches of 32 nodes) ----
    for (int bi = 0; bi < 8; ++bi) {
        int ln = bi * 32 + lnb;
        long g = row0 + ln;
        if (g < n) {
            int p0 = rp[g], p1 = rp[g + 1];
            float ax = 0.0f, ay = 0.0f, az = 0.0f, aw = 0.0f;
            for (int k = p0; k < p1; k += 8) {
                int last = p1 - 1;
                int idx[8];
#pragma unroll
                for (int q = 0; q < 8; ++q) {
                    int e = k + q;
                    idx[q] = col[e < p1 ? e : last];
                }
                float4 v[8];
#pragma unroll
                for (int q = 0; q < 8; ++q)
                    v[q] = *(const float4*)(preL + (size_t)idx[q] * HID + u * 4);
#pragma unroll
                for (int q = 0; q < 8; ++q) {
                    if (k + q < p1) {
                        ax += v[q].x; ay += v[q].y; az += v[q].z; aw += v[q].w;
                    }
                }
            }
            float inv = 1.0f / fmaxf((float)(p1 - p0), 1.0f);
            float4 r = *(const float4*)(preR + (size_t)g * HID + u * 4);
            float* hp = &hh[ln * HSTR + u * 4];
            hp[0] = fmaxf(__builtin_fmaf(ax, inv, r.x), 0.0f);
            hp[1] = fmaxf(__builtin_fmaf(ay, inv, r.y), 0.0f);
            hp[2] = fmaxf(__builtin_fmaf(az, inv, r.z), 0.0f);
            hp[3] = fmaxf(__builtin_fmaf(aw, inv, r.w), 0.0f);
        }
    }
    __syncthreads();

    // ---- phase 2: dense epilogue, thread t = node row0+t ----
    long gd = row0 + t;
    if (gd >= n) return;
    float rrow[32];
#pragma unroll
    for (int q = 0; q < 8; ++q) {
        float4 v = *(const float4*)(&hh[t * HSTR + q * 4]);
        rrow[q * 4] = v.x; rrow[q * 4 + 1] = v.y;
        rrow[q * 4 + 2] = v.z; rrow[q * 4 + 3] = v.w;
    }

    if (EP == 2) {
        float o0 = bA[0], o1 = bA[1];
#pragma unroll
        for (int k = 0; k < HID; ++k) {
            o0 = __builtin_fmaf(rrow[k], wA[k * 2 + 0], o0);
            o1 = __builtin_fmaf(rrow[k], wA[k * 2 + 1], o1);
        }
        outA[gd * 2 + 0] = o0;
        outA[gd * 2 + 1] = o1;
        return;
    }

    // pass A
    {
        float acc[HID];
#pragma unroll
        for (int j = 0; j < HID; ++j) acc[j] = bA ? bA[j] : 0.0f;
#pragma unroll
        for (int k = 0; k < HID; ++k) {
            float rk = rrow[k];
            const float* wr = wA + k * HID;
#pragma unroll
            for (int j = 0; j < HID; ++j) acc[j] = __builtin_fmaf(rk, wr[j], acc[j]);
        }
        float* o = outA + (size_t)gd * HID;
#pragma unroll
        for (int j = 0; j < HID; j += 4)
            *(float4*)(o + j) = make_float4(acc[j], acc[j + 1], acc[j + 2], acc[j + 3]);
    }
    if (EP == 0) {
        float acc[HID];
#pragma unroll
        for (int j = 0; j < HID; ++j) acc[j] = bB[j];
#pragma unroll
        for (int k = 0; k < HID; ++k) {
            float rk = rrow[k];
            const float* wr = wB + k * HID;
#pragma unroll
            for (int j = 0; j < HID; ++j) acc[j] = __builtin_fmaf(rk, wr[j], acc[j]);
        }
        float* o = outB + (size_t)gd * HID;
#pragma unroll
        for (int j = 0; j < HID; j += 4)
            *(float4*)(o + j) = make_float4(acc[j], acc[j + 1], acc[j + 2], acc[j + 3]);
    }
}

// ============================================================================

extern "C" void kernel_launch(void* const* d_in, const int* in_sizes, int n_in,
                              void* d_out, int out_size, void* d_ws, size_t ws_size,
                              hipStream_t stream) {
    const float* x_addr  = (const float*)d_in[0];
    const float* x_tx    = (const float*)d_in[1];
    const int*   ei_at   = (const int*)d_in[2];
    const int*   ei_ta   = (const int*)d_in[3];
    const float* w1_tx_l = (const float*)d_in[4];  const float* b1_tx = (const float*)d_in[5];
    const float* w1_tx_r = (const float*)d_in[6];
    const float* w1_ad_l = (const float*)d_in[7];  const float* b1_ad = (const float*)d_in[8];
    const float* w1_ad_r = (const float*)d_in[9];
    const float* w2_tx_l = (const float*)d_in[10]; const float* b2_tx = (const float*)d_in[11];
    const float* w2_tx_r = (const float*)d_in[12];
    const float* w2_ad_l = (const float*)d_in[13]; const float* b2_ad = (const float*)d_in[14];
    const float* w2_ad_r = (const float*)d_in[15];
    // d_in[16..18] unused (w3_tx_*)
    const float* w3_ad_l = (const float*)d_in[19]; const float* b3_ad = (const float*)d_in[20];
    const float* w3_ad_r = (const float*)d_in[21];
    const float* w_out   = (const float*)d_in[22]; const float* b_out = (const float*)d_in[23];
    float* out = (float*)d_out;

    // ---- workspace carve (5 slots, round-10-proven footprint) ----
    char* base = (char*)d_ws;
    int* bcnt   = (int*)base;  base += (size_t)(2 * NB) * 4;
    int* bbase  = (int*)base;  base += (size_t)(2 * (NB + 1)) * 4;
    int* gcur   = (int*)base;  base += (size_t)(2 * NB) * 4;
    int* rp_tx  = (int*)base;  base += (size_t)(NND + 1) * 4;
    int* rp_ad  = (int*)base;  base += (size_t)(NND + 1) * 4;
    int* col_at = (int*)base;  base += (size_t)NEDGE * 4;
    int* col_ta = (int*)base;  base += (size_t)NEDGE * 4;
    base = (char*)(((size_t)base + 255) & ~(size_t)255);
    const size_t SLOT = (size_t)NND * HID;
    float* SE = (float*)base;                    // overlays eb region (dead after build)
    unsigned* eb_at = (unsigned*)base;           // build-only
    unsigned* eb_ta = eb_at + (size_t)NEDGE;
    float* SA = SE + SLOT;
    float* SB = SA + SLOT;
    float* SC = SB + SLOT;
    float* SD = SC + SLOT;

    dim3 blk(256);
    dim3 blk128(128);
    int gS = cdiv_host(NND, 128);                 // 3125 (k_preS2)
    int gB = cdiv_host(NND, 256);                 // 1563 (k_aggE: 256 nodes/block)
    const int GH = 96, GD = 192;

    // ---- bucketed CSR build ----
    hipMemsetAsync(bcnt, 0, (size_t)(2 * NB) * 4, stream);
    k_hist<<<2 * GH, blk, 0, stream>>>(ei_at + NEDGE, ei_ta + NEDGE, bcnt, GH);
    k_scan_nb<<<2, blk, 0, stream>>>(bcnt, bbase, gcur);
    k_dist<<<2 * GD, blk, 0, stream>>>(ei_at, ei_ta, gcur, eb_at, eb_ta, GD);
    k_csrb<<<2 * NB, blk, 0, stream>>>(eb_at, eb_ta, bbase, rp_tx, rp_ad, col_at, col_ta);

    // ---- layer 1 pre-transforms (dual: each x read once) ----
    // SA = x_addr@w1_tx_l (pL-tx)   SB = x_addr@w1_ad_r + b1_ad (pR-ad)
    k_preS2<<<gS, blk128, 0, stream>>>(x_addr, w1_tx_l, SA, w1_ad_r, b1_ad, SB, NADDR);
    // SC = x_tx@w1_ad_l (pL-ad)     SD = x_tx@w1_tx_r + b1_tx (pR-tx)
    k_preS2<<<gS, blk128, 0, stream>>>(x_tx, w1_ad_l, SC, w1_tx_r, b1_tx, SD, NTX);

    // ---- L1 aggs with fused L2 pre-transforms ----
    // TX agg: gather SA over at, self SD. Epilogue: SE = TX@w2_ad_l (P1),
    //         SD = TX@w2_tx_r + b2_tx (P2, in-place on preR).
    k_aggE<0><<<gB, blk, 0, stream>>>(rp_tx, col_at, SA, SD,
                                      w2_ad_l, nullptr, SE,
                                      w2_tx_r, b2_tx, SD, NTX);
    // AD agg: gather SC over ta, self SB. Epilogue: SA = AD@w2_tx_l (P3),
    //         SB = AD@w2_ad_r + b2_ad (P4, in-place on preR).
    k_aggE<0><<<gB, blk, 0, stream>>>(rp_ad, col_ta, SC, SB,
                                      w2_tx_l, nullptr, SA,
                                      w2_ad_r, b2_ad, SB, NADDR);

    // ---- L2 aggs with fused L3 pre-transforms ----
    // TX2 agg: gather SA (P3) over at, self SD (P2). Epilogue: SC = TX2@w3_ad_l (Q1).
    k_aggE<1><<<gB, blk, 0, stream>>>(rp_tx, col_at, SA, SD,
                                      w3_ad_l, nullptr, SC,
                                      nullptr, nullptr, nullptr, NTX);
    // AD2 agg: gather SE (P1) over ta, self SB (P4). Epilogue: SB = AD2@w3_ad_r + b3_ad (Q2).
    k_aggE<1><<<gB, blk, 0, stream>>>(rp_ad, col_ta, SE, SB,
                                      w3_ad_r, b3_ad, SB,
                                      nullptr, nullptr, nullptr, NADDR);

    // ---- L3 agg + classifier ----
    k_aggE<2><<<gB, blk, 0, stream>>>(rp_ad, col_ta, SC, SB,
                                      w_out, b_out, out,
                                      nullptr, nullptr, nullptr, NADDR);
}